// Round 11
// baseline (667.284 us; speedup 1.0000x reference)
//
#include <hip/hip_runtime.h>
#include <stdint.h>

// ---------------------------------------------------------------------------
// AttentionHead: Q/K/V projection (bf16x3 MFMA, writes attention-native
// buffers) + MFMA flash attention (swapped-QK^T, in-register softmax+dropout)
// + key-compaction. JAX-exact dropout (threefry2x32 key=42, o0^o1 fold).
//
// HISTORY: r6 PASS fp32 (1184us) | r8 PASS qkv-MFMA (847us) | r9 PASS
// attn-MFMA (533us; attn 232us: VALUBusy 58%, MfmaUtil 6.4%, conflicts 3e7).
// r10 (unbenchmarked, GPU timeout): panel-split staging. r11 AUDIT FIX:
// r10's uint4 K-staging into [32][132] rows (264B stride) was ds_write_b128
// at 8B-aligned addresses on odd rows -> UB. Staged via uint2 (8B) instead,
// r9-validated granularity/banking. Quantization points IDENTICAL to r9.
#define PRNG_VARIANT 2
// ---------------------------------------------------------------------------

#define B_ 16
#define S_ 2048
#define D_ 1024
#define H_ 128
#define SCALE_ 0.08838834764831845f  /* 1/sqrt(128) */
#define KEEPP_ 0.7f

typedef __attribute__((ext_vector_type(8))) short bf16x8_t;
typedef __attribute__((ext_vector_type(4))) float f32x4_t;

__device__ __forceinline__ void threefry2x32(uint32_t x0, uint32_t x1,
                                             uint32_t& o0, uint32_t& o1) {
  // key = (0, 42); ks2 = 0 ^ 42 ^ 0x1BD11BDA
  const uint32_t ks0 = 0u, ks1 = 42u, ks2 = 0x1BD11BF0u;
  x0 += ks0; x1 += ks1;
#define TF_R(r) { x0 += x1; x1 = (x1 << (r)) | (x1 >> (32 - (r))); x1 ^= x0; }
  TF_R(13) TF_R(15) TF_R(26) TF_R(6)
  x0 += ks1; x1 += ks2 + 1u;
  TF_R(17) TF_R(29) TF_R(16) TF_R(24)
  x0 += ks2; x1 += ks0 + 2u;
  TF_R(13) TF_R(15) TF_R(26) TF_R(6)
  x0 += ks0; x1 += ks1 + 3u;
  TF_R(17) TF_R(29) TF_R(16) TF_R(24)
  x0 += ks1; x1 += ks2 + 4u;
  TF_R(13) TF_R(15) TF_R(26) TF_R(6)
  x0 += ks2; x1 += ks0 + 5u;
#undef TF_R
  o0 = x0; o1 = x1;
}

__device__ __forceinline__ bool keep_rand(uint32_t n) {
  uint32_t o0, o1;
  threefry2x32(0u, n, o0, o1);
  uint32_t bits = o0 ^ o1;      // partitionable 32-bit fold (VERIFIED r6-r9)
  float u = __uint_as_float((bits >> 9) | 0x3F800000u) - 1.0f;
  return u < KEEPP_;
}

// round-to-nearest-even fp32 -> bf16 (finite inputs)
__device__ __forceinline__ uint16_t bf16_rne(float f) {
  uint32_t u = __float_as_uint(f);
  return (uint16_t)((u + 0x7FFFu + ((u >> 16) & 1u)) >> 16);
}

// frag load: two uint2 at (base + off0), (base + off1) -> bf16x8 (8B aligned)
__device__ __forceinline__ bf16x8_t ldf(const ushort* base, int off0, int off1) {
  union { uint2 d[2]; bf16x8_t v; } u;
  u.d[0] = *(const uint2*)(base + off0);
  u.d[1] = *(const uint2*)(base + off1);
  return u.v;
}

// V^T frag: rows only 4B-aligned -> paired b32 loads (ds_read2_b32)
__device__ __forceinline__ bf16x8_t ldvf(const ushort* rowp, int g) {
  union { uint d[4]; bf16x8_t v; } u;
  u.d[0] = *(const uint*)(rowp + 4 * g);
  u.d[1] = *(const uint*)(rowp + 4 * g + 2);
  u.d[2] = *(const uint*)(rowp + 16 + 4 * g);
  u.d[3] = *(const uint*)(rowp + 16 + 4 * g + 2);
  return u.v;
}

// ---------------------------------------------------------------------------
// Kernel 0: per-batch compaction of unmasked key indices (unchanged).
// ---------------------------------------------------------------------------
__global__ __launch_bounds__(64) void mask_scan(
    const int* __restrict__ amask,
    int* __restrict__ kidx, int* __restrict__ ncomp) {
  const int b = blockIdx.x;
  const int lane = threadIdx.x;
  const int* m = amask + b * S_;
  int* outp = kidx + b * S_;
  int base = 0;
  for (int c = 0; c < S_; c += 64) {
    const int mv = m[c + lane];
    const unsigned long long bal = __ballot(mv != 0);
    const int off = __popcll(bal & ((1ull << lane) - 1ull));
    if (mv != 0) outp[base + off] = c + lane;
    base += (int)__popcll(bal);
  }
  if (lane == 0) ncomp[b] = base;
  for (int i = base + lane; i < S_; i += 64) outp[i] = 0;
}

// ---------------------------------------------------------------------------
// Kernel 1: qkv projection via bf16x3 MFMA (r8-validated core).
// Panel-specific epilogues: by=0 Q fp32 [m][128]; by=1 K -> Kh,Kl bf16
// panels (hi/lo split once); by=2 V -> bf16 panel.
// ---------------------------------------------------------------------------
__device__ __forceinline__ bf16x8_t ld_frag(const ushort T[128][36], int row, int g) {
  union { uint2 d[2]; bf16x8_t v; } u;
  u.d[0] = *(const uint2*)&T[row][g << 2];
  u.d[1] = *(const uint2*)&T[row][16 + (g << 2)];
  return u.v;
}

__global__ __launch_bounds__(256) void qkv_mfma(
    const float* __restrict__ x,
    const float* __restrict__ qw, const float* __restrict__ qb,
    const float* __restrict__ kw, const float* __restrict__ kb,
    const float* __restrict__ vw, const float* __restrict__ vb,
    float* __restrict__ qbuf, ushort* __restrict__ khbuf,
    ushort* __restrict__ klbuf, ushort* __restrict__ vbuf) {
  __shared__ ushort Xh[128][36], Xl[128][36], Wh[128][36], Wl[128][36];

  const int tid = threadIdx.x;
  const int m0  = blockIdx.x * 128;
  const int by  = blockIdx.y;
  const float* wsrc = (by == 0) ? qw : (by == 1) ? kw : vw;
  const float* bias = (by == 0) ? qb : (by == 1) ? kb : vb;

  const int wid = tid >> 6, lane = tid & 63;
  const int wy = wid >> 1, wx = wid & 1;
  const int lm = lane & 15, g = lane >> 4;

  const int srow = tid >> 3;
  const int sc4  = (tid & 7) << 2;

  f32x4_t acc[4][4];
#pragma unroll
  for (int i = 0; i < 4; ++i)
#pragma unroll
    for (int j = 0; j < 4; ++j) acc[i][j] = (f32x4_t){0.f, 0.f, 0.f, 0.f};

  for (int k0 = 0; k0 < D_; k0 += 32) {
    __syncthreads();
#pragma unroll
    for (int i = 0; i < 4; ++i) {
      const int row = srow + (i << 5);
      {
        float4 v = *(const float4*)(x + (size_t)(m0 + row) * D_ + k0 + sc4);
        uint16_t h0 = bf16_rne(v.x), h1 = bf16_rne(v.y),
                 h2 = bf16_rne(v.z), h3 = bf16_rne(v.w);
        float r0 = v.x - __uint_as_float((uint32_t)h0 << 16);
        float r1 = v.y - __uint_as_float((uint32_t)h1 << 16);
        float r2 = v.z - __uint_as_float((uint32_t)h2 << 16);
        float r3 = v.w - __uint_as_float((uint32_t)h3 << 16);
        *(uint2*)&Xh[row][sc4] = make_uint2((uint32_t)h0 | ((uint32_t)h1 << 16),
                                            (uint32_t)h2 | ((uint32_t)h3 << 16));
        *(uint2*)&Xl[row][sc4] = make_uint2(
            (uint32_t)bf16_rne(r0) | ((uint32_t)bf16_rne(r1) << 16),
            (uint32_t)bf16_rne(r2) | ((uint32_t)bf16_rne(r3) << 16));
      }
      {
        float4 v = *(const float4*)(wsrc + (size_t)row * D_ + k0 + sc4);
        uint16_t h0 = bf16_rne(v.x), h1 = bf16_rne(v.y),
                 h2 = bf16_rne(v.z), h3 = bf16_rne(v.w);
        float r0 = v.x - __uint_as_float((uint32_t)h0 << 16);
        float r1 = v.y - __uint_as_float((uint32_t)h1 << 16);
        float r2 = v.z - __uint_as_float((uint32_t)h2 << 16);
        float r3 = v.w - __uint_as_float((uint32_t)h3 << 16);
        *(uint2*)&Wh[row][sc4] = make_uint2((uint32_t)h0 | ((uint32_t)h1 << 16),
                                            (uint32_t)h2 | ((uint32_t)h3 << 16));
        *(uint2*)&Wl[row][sc4] = make_uint2(
            (uint32_t)bf16_rne(r0) | ((uint32_t)bf16_rne(r1) << 16),
            (uint32_t)bf16_rne(r2) | ((uint32_t)bf16_rne(r3) << 16));
      }
    }
    __syncthreads();

    bf16x8_t Ah[4], Al[4], Bh[4], Bl[4];
#pragma unroll
    for (int mi = 0; mi < 4; ++mi) {
      const int r = (wy << 6) + (mi << 4) + lm;
      Ah[mi] = ld_frag(Xh, r, g);
      Al[mi] = ld_frag(Xl, r, g);
    }
#pragma unroll
    for (int ni = 0; ni < 4; ++ni) {
      const int r = (wx << 6) + (ni << 4) + lm;
      Bh[ni] = ld_frag(Wh, r, g);
      Bl[ni] = ld_frag(Wl, r, g);
    }
#pragma unroll
    for (int mi = 0; mi < 4; ++mi)
#pragma unroll
      for (int ni = 0; ni < 4; ++ni) {
        acc[mi][ni] = __builtin_amdgcn_mfma_f32_16x16x32_bf16(
            Ah[mi], Bh[ni], acc[mi][ni], 0, 0, 0);
        acc[mi][ni] = __builtin_amdgcn_mfma_f32_16x16x32_bf16(
            Ah[mi], Bl[ni], acc[mi][ni], 0, 0, 0);
        acc[mi][ni] = __builtin_amdgcn_mfma_f32_16x16x32_bf16(
            Al[mi], Bh[ni], acc[mi][ni], 0, 0, 0);
      }
  }

  // epilogue: D row=(l>>4)*4+reg, col=l&15 (m89-verified); panel-specific out
#pragma unroll
  for (int mi = 0; mi < 4; ++mi) {
    const int row = m0 + (wy << 6) + (mi << 4) + (g << 2);
#pragma unroll
    for (int ni = 0; ni < 4; ++ni) {
      const int nl = (wx << 6) + (ni << 4) + lm;
      const float bv = bias[nl];
#pragma unroll
      for (int r = 0; r < 4; ++r) {
        const float val = acc[mi][ni][r] + bv;
        const size_t idx = (size_t)(row + r) * H_ + nl;
        if (by == 0) {
          qbuf[idx] = val;
        } else if (by == 1) {
          uint16_t h = bf16_rne(val);
          khbuf[idx] = h;
          klbuf[idx] = bf16_rne(val - __uint_as_float((uint32_t)h << 16));
        } else {
          vbuf[idx] = bf16_rne(val);
        }
      }
    }
  }
}

// ---------------------------------------------------------------------------
// Kernel 2: MFMA flash attention over compacted keys (r9-validated math).
// Staging = pure copies from Kh/Kl/V panels (zero cvt ALU). K staged via
// uint2 (8B, alignment-safe for 264B row stride). V^T LDS [128][34]:
// writes 4-way aliased, reads conflict-free via paired b32.
// Block 128 thr = 2 waves; wave w owns 16 q-rows. Swapped QK^T (bf16x3),
// in-register softmax+dropout (l = PRE-dropout sums), PV mfma.
// LDS: KhS/KlS[32][132] + Vt[128][34] + kidx_s = 25.8 KB.
// ---------------------------------------------------------------------------
__global__ __launch_bounds__(128) void attn_mfma(
    const float* __restrict__ qbuf,
    const ushort* __restrict__ khbuf,
    const ushort* __restrict__ klbuf,
    const ushort* __restrict__ vbuf,
    const int* __restrict__ kidx,
    const int* __restrict__ ncomp,
    float* __restrict__ out) {
  __shared__ ushort KhS[32][132], KlS[32][132];
  __shared__ ushort Vt[128][34];
  __shared__ int kidx_s[32];

  const int b   = blockIdx.y;
  const int q0  = blockIdx.x * 32;
  const int tid = threadIdx.x;
  const int wid = tid >> 6, lane = tid & 63;
  const int g = lane >> 4, lm = lane & 15;
  const int nc = ncomp[b];
  const int* kidx_b = kidx + b * S_;
  const int qrow = q0 + wid * 16 + lm;   // softmax-side q of this lane

  const ushort* khp = khbuf + (size_t)b * S_ * H_;
  const ushort* klp = klbuf + (size_t)b * S_ * H_;
  const ushort* vbp = vbuf + (size_t)b * S_ * H_;

  // hoist Q B-frags (pre-scaled, hi/lo split). B-frag: n=lm, k={4g..,16+4g..}
  bf16x8_t Qh[4], Ql[4];
  {
    const float* qptr = qbuf + (size_t)(b * S_ + qrow) * H_;
#pragma unroll
    for (int c = 0; c < 4; ++c) {
      float4 ea = *(const float4*)(qptr + 32 * c + 4 * g);
      float4 eb = *(const float4*)(qptr + 32 * c + 16 + 4 * g);
      float f[8] = {ea.x, ea.y, ea.z, ea.w, eb.x, eb.y, eb.z, eb.w};
      union { ushort u[8]; bf16x8_t v; } hh, ll;
#pragma unroll
      for (int e = 0; e < 8; ++e) {
        float s = f[e] * SCALE_;
        ushort h = bf16_rne(s);
        hh.u[e] = h;
        ll.u[e] = bf16_rne(s - __uint_as_float((uint32_t)h << 16));
      }
      Qh[c] = hh.v; Ql[c] = ll.v;
    }
  }

  f32x4_t acc[8];
#pragma unroll
  for (int t = 0; t < 8; ++t) acc[t] = (f32x4_t){0.f, 0.f, 0.f, 0.f};
  float m_run = -INFINITY, l_run = 0.f;
  const uint32_t nq = (uint32_t)(b * S_ + qrow) << 11;

  for (int kt = 0; kt < nc; kt += 32) {
    __syncthreads();   // prev tile's frag reads done
    if (tid < 32) kidx_s[tid] = kidx_b[kt + tid];
    // stage K hi/lo: uint2 copies (8B-aligned for any row; r9 banking)
#pragma unroll
    for (int i = 0; i < 8; ++i) {
      int flat = i * 128 + tid;                   // 0..1023
      int key = flat >> 5, c4 = (flat & 31) << 2; // 32 uint2-chunks per row
      int krow = kidx_b[kt + key];
      *(uint2*)&KhS[key][c4] = *(const uint2*)(khp + (size_t)krow * H_ + c4);
      *(uint2*)&KlS[key][c4] = *(const uint2*)(klp + (size_t)krow * H_ + c4);
    }
    // stage V^T: uint2 loads (4 bf16), scalar u16 transpose writes (4-way)
#pragma unroll
    for (int i = 0; i < 8; ++i) {
      int flat = i * 128 + tid;
      int key = flat >> 5, c4 = (flat & 31) << 2;
      int krow = kidx_b[kt + key];
      uint2 v = *(const uint2*)(vbp + (size_t)krow * H_ + c4);
      Vt[c4 + 0][key] = (ushort)(v.x & 0xffffu);
      Vt[c4 + 1][key] = (ushort)(v.x >> 16);
      Vt[c4 + 2][key] = (ushort)(v.y & 0xffffu);
      Vt[c4 + 3][key] = (ushort)(v.y >> 16);
    }
    __syncthreads();

    // swapped QK^T: s0 = keys 0-15, s1 = keys 16-31 (bf16x3)
    f32x4_t s0 = (f32x4_t){0.f, 0.f, 0.f, 0.f};
    f32x4_t s1 = (f32x4_t){0.f, 0.f, 0.f, 0.f};
#pragma unroll
    for (int c = 0; c < 4; ++c) {
      const int o0 = 32 * c + 4 * g, o1 = 32 * c + 16 + 4 * g;
      bf16x8_t a0h = ldf(&KhS[lm][0], o0, o1);
      bf16x8_t a0l = ldf(&KlS[lm][0], o0, o1);
      bf16x8_t a1h = ldf(&KhS[lm + 16][0], o0, o1);
      bf16x8_t a1l = ldf(&KlS[lm + 16][0], o0, o1);
      s0 = __builtin_amdgcn_mfma_f32_16x16x32_bf16(a0h, Qh[c], s0, 0, 0, 0);
      s0 = __builtin_amdgcn_mfma_f32_16x16x32_bf16(a0l, Qh[c], s0, 0, 0, 0);
      s0 = __builtin_amdgcn_mfma_f32_16x16x32_bf16(a0h, Ql[c], s0, 0, 0, 0);
      s1 = __builtin_amdgcn_mfma_f32_16x16x32_bf16(a1h, Qh[c], s1, 0, 0, 0);
      s1 = __builtin_amdgcn_mfma_f32_16x16x32_bf16(a1l, Qh[c], s1, 0, 0, 0);
      s1 = __builtin_amdgcn_mfma_f32_16x16x32_bf16(a1h, Ql[c], s1, 0, 0, 0);
    }

    // kill tail slots, online softmax (lane owns q=lm; keys 4g+r, 16+4g+r)
    float sv0[4], sv1[4];
#pragma unroll
    for (int r = 0; r < 4; ++r) {
      sv0[r] = (kt + 4 * g + r      < nc) ? s0[r] : -INFINITY;
      sv1[r] = (kt + 16 + 4 * g + r < nc) ? s1[r] : -INFINITY;
    }
    float tm = fmaxf(fmaxf(fmaxf(sv0[0], sv0[1]), fmaxf(sv0[2], sv0[3])),
                     fmaxf(fmaxf(sv1[0], sv1[1]), fmaxf(sv1[2], sv1[3])));
    tm = fmaxf(tm, __shfl_xor(tm, 16));
    tm = fmaxf(tm, __shfl_xor(tm, 32));
    float mn = fmaxf(m_run, tm);

    float p0[4], p1[4], ps = 0.f;
#pragma unroll
    for (int r = 0; r < 4; ++r) {
      p0[r] = (sv0[r] == -INFINITY) ? 0.f : __expf(sv0[r] - mn);
      p1[r] = (sv1[r] == -INFINITY) ? 0.f : __expf(sv1[r] - mn);
      ps += p0[r] + p1[r];
    }
    ps += __shfl_xor(ps, 16);
    ps += __shfl_xor(ps, 32);

    float rf = (m_run == mn) ? 1.f : __expf(m_run - mn);
    l_run = l_run * rf + ps;
    m_run = mn;

    // rescale acc (acc rows are q = 4g+r -> fetch those q's factors)
    float fr0 = __shfl(rf, 4 * g + 0);
    float fr1 = __shfl(rf, 4 * g + 1);
    float fr2 = __shfl(rf, 4 * g + 2);
    float fr3 = __shfl(rf, 4 * g + 3);
#pragma unroll
    for (int t = 0; t < 8; ++t) {
      acc[t][0] *= fr0; acc[t][1] *= fr1; acc[t][2] *= fr2; acc[t][3] *= fr3;
    }

    // dropout (original key index) + pack P as bf16 A-frag
    union { ushort u[8]; bf16x8_t v; } pk;
#pragma unroll
    for (int r = 0; r < 4; ++r) {
      float dv0 = keep_rand(nq + (uint32_t)kidx_s[4 * g + r])      ? p0[r] : 0.f;
      float dv1 = keep_rand(nq + (uint32_t)kidx_s[16 + 4 * g + r]) ? p1[r] : 0.f;
      pk.u[r]     = bf16_rne(dv0);
      pk.u[4 + r] = bf16_rne(dv1);
    }

    // PV: acc[ht] += P * V  (D[q=(l>>4)*4+r][h=ht*16+lm])
#pragma unroll
    for (int ht = 0; ht < 8; ++ht) {
      bf16x8_t vf = ldvf(&Vt[ht * 16 + lm][0], g);
      acc[ht] = __builtin_amdgcn_mfma_f32_16x16x32_bf16(pk.v, vf, acc[ht], 0, 0, 0);
    }
  }

  // epilogue: normalize by this acc-row's l (cross-layout via shfl)
  float iv[4];
#pragma unroll
  for (int r = 0; r < 4; ++r) {
    float lq = __shfl(l_run, 4 * g + r);
    iv[r] = 1.0f / (lq * KEEPP_);
  }
#pragma unroll
  for (int ht = 0; ht < 8; ++ht) {
#pragma unroll
    for (int r = 0; r < 4; ++r) {
      const int q = q0 + wid * 16 + 4 * g + r;
      out[(size_t)(b * S_ + q) * H_ + ht * 16 + lm] = acc[ht][r] * iv[r];
    }
  }
}

// ---------------------------------------------------------------------------
extern "C" void kernel_launch(void* const* d_in, const int* in_sizes, int n_in,
                              void* d_out, int out_size, void* d_ws, size_t ws_size,
                              hipStream_t stream) {
  (void)in_sizes; (void)n_in; (void)out_size; (void)ws_size;
  const float* x  = (const float*)d_in[0];
  const int* am   = (const int*)d_in[1];
  const float* qw = (const float*)d_in[2];
  const float* qb = (const float*)d_in[3];
  const float* kw = (const float*)d_in[4];
  const float* kb = (const float*)d_in[5];
  const float* vw = (const float*)d_in[6];
  const float* vb = (const float*)d_in[7];
  float* out = (float*)d_out;

  // ws layout (42.1 MB total, < 48.1 MB used through r9):
  //   qbuf fp32 [B][S][128] 16.78MB | kh 8.39 | kl 8.39 | vb 8.39 | kidx | ncomp
  const size_t NE = (size_t)B_ * S_ * H_;   // 4,194,304 elements
  float*  qbuf  = (float*)d_ws;
  ushort* khbuf = (ushort*)((char*)d_ws + NE * 4);
  ushort* klbuf = khbuf + NE;
  ushort* vbuf  = klbuf + NE;
  int*    kidx  = (int*)(vbuf + NE);
  int*    ncomp = kidx + B_ * S_;

  mask_scan<<<B_, 64, 0, stream>>>(am, kidx, ncomp);
  qkv_mfma<<<dim3((B_ * S_) / 128, 3), 256, 0, stream>>>(
      x, qw, qb, kw, kb, vw, vb, qbuf, khbuf, klbuf, vbuf);
  attn_mfma<<<dim3(S_ / 32, B_), 128, 0, stream>>>(
      qbuf, khbuf, klbuf, vbuf, kidx, ncomp, out);
}